// Round 6
// baseline (310.959 us; speedup 1.0000x reference)
//
#include <hip/hip_runtime.h>
#include <math.h>

// Problem constants (fixed by the reference)
#define BB   2
#define SS   2304
#define DINC 1024
#define DIMC 1024
#define HH   16
#define HD   64

typedef _Float16 half_t;
typedef __attribute__((ext_vector_type(4))) _Float16 half4;   // 2 VGPRs
typedef __attribute__((ext_vector_type(8))) _Float16 half8;   // 4 VGPRs
typedef __attribute__((ext_vector_type(4))) float    f32x4;   // 4 VGPRs

#define LOG2E 1.44269504088896340736f

// async global->LDS, 16B per lane; LDS dest = wave-uniform base + lane*16
#define GLOAD_LDS16(gp, lp)                                                     \
    __builtin_amdgcn_global_load_lds(                                           \
        (const __attribute__((address_space(1))) void*)(gp),                    \
        (__attribute__((address_space(3))) void*)(lp), 16, 0, 0)

// ---------------------------------------------------------------------------
// Converter: fp32 row-major [R][K] -> f16 tile-blocked [R/RB][K/32][RB][32].
// ---------------------------------------------------------------------------
template<int RB>
__global__ __launch_bounds__(256)
void convert_tile_f16(const float* __restrict__ src, half_t* __restrict__ dst, int K)
{
    constexpr int EPT = RB * 32 / 256;       // elements per thread (16 or 8)
    const int mb = blockIdx.x;
    const int kb = blockIdx.y;
    const int t  = threadIdx.x;
    const int e0 = t * EPT;
    const int mm = e0 >> 5;
    const int kk = e0 & 31;
    const float* sp = src + (size_t)(mb * RB + mm) * K + kb * 32 + kk;
    half_t*      dp = dst + ((size_t)mb * (K >> 5) + kb) * (RB * 32) + mm * 32 + kk;
    #pragma unroll
    for (int g = 0; g < EPT / 4; ++g) {
        float4 v = *(const float4*)(sp + 4 * g);
        dp[4 * g + 0] = (half_t)v.x; dp[4 * g + 1] = (half_t)v.y;
        dp[4 * g + 2] = (half_t)v.z; dp[4 * g + 3] = (half_t)v.w;
    }
}

// ---------------------------------------------------------------------------
// f16 MFMA GEMM (NT): C[m][n] = sum_k A[m][k]*W[n][k] + bias[n], fp32 accum.
// BM=128 fixed; BN=128 (2x2 waves, 64x64 wave tile) or BN=64 (4x1 waves,
// 32x64 wave tile -> 2x the blocks for small-N proj GEMM occupancy).
// A blocked [mb][kb][128][32]; B blocked [nb][kb][BN][32]. K-loop unrolled x2.
// ---------------------------------------------------------------------------
template<int BN, bool OUT_HALF>
__global__ __launch_bounds__(256)
void gemm_mfma(const half_t* __restrict__ Ah, const half_t* __restrict__ Bh,
               const float* __restrict__ bias, void* __restrict__ Cout,
               int M, int N, int K)
{
    constexpr int MT = (BN == 128) ? 4 : 2;
    constexpr int NT = 4;
    const int KB = K >> 5;
    __shared__ half_t As[8192];          // [u][128][32]
    __shared__ half_t Bs[2 * BN * 32];   // [u][BN][32]

    const int t    = threadIdx.x;
    const int w    = t >> 6;
    const int lane = t & 63;
    const int l15  = lane & 15, quad = lane >> 4;
    const int wr   = (BN == 128) ? (w >> 1) : w;
    const int wc   = (BN == 128) ? (w & 1) : 0;
    const int mb   = blockIdx.y, nb = blockIdx.x;

    f32x4 acc[MT][NT];
    #pragma unroll
    for (int mt = 0; mt < MT; ++mt)
        #pragma unroll
        for (int nt = 0; nt < NT; ++nt) acc[mt][nt] = (f32x4){0.f, 0.f, 0.f, 0.f};

    const half_t* atile = Ah + (size_t)mb * KB * 4096;
    const half_t* btile = Bh + (size_t)nb * KB * (BN * 32);

    for (int kb = 0; kb < KB; kb += 2) {
        #pragma unroll
        for (int u = 0; u < 2; ++u) {
            const half_t* at = atile + (size_t)(kb + u) * 4096;
            const half_t* bt = btile + (size_t)(kb + u) * (BN * 32);
            #pragma unroll
            for (int v = 0; v < 2; ++v) {
                const int ch = w * 2 + v;
                GLOAD_LDS16(at + ch * 512 + lane * 8, As + u * 4096 + ch * 512);
            }
            if (BN == 128) {
                #pragma unroll
                for (int v = 0; v < 2; ++v) {
                    const int ch = w * 2 + v;
                    GLOAD_LDS16(bt + ch * 512 + lane * 8, Bs + u * 4096 + ch * 512);
                }
            } else {
                GLOAD_LDS16(bt + w * 512 + lane * 8, Bs + u * (BN * 32) + w * 512);
            }
        }
        __syncthreads();

        #pragma unroll
        for (int u = 0; u < 2; ++u) {
            half8 af[MT], bf[NT];
            #pragma unroll
            for (int mt = 0; mt < MT; ++mt)
                af[mt] = *(const half8*)(As + u * 4096
                                         + (wr * (MT * 16) + mt * 16 + l15) * 32 + quad * 8);
            #pragma unroll
            for (int nt = 0; nt < NT; ++nt)
                bf[nt] = *(const half8*)(Bs + u * (BN * 32)
                                         + (wc * 64 + nt * 16 + l15) * 32 + quad * 8);
            #pragma unroll
            for (int mt = 0; mt < MT; ++mt)
                #pragma unroll
                for (int nt = 0; nt < NT; ++nt)
                    acc[mt][nt] = __builtin_amdgcn_mfma_f32_16x16x32_f16(
                        af[mt], bf[nt], acc[mt][nt], 0, 0, 0);
        }
        __syncthreads();
    }

    // epilogue: D[m = quad*4+reg][n = l15] per 16x16 tile, + bias
    const int bm = mb * 128, bn = nb * BN;
    #pragma unroll
    for (int nt = 0; nt < NT; ++nt) {
        const int n  = bn + wc * 64 + nt * 16 + l15;
        const float bv = bias[n];
        #pragma unroll
        for (int mt = 0; mt < MT; ++mt) {
            const int m0 = bm + wr * (MT * 16) + mt * 16 + quad * 4;
            #pragma unroll
            for (int rg = 0; rg < 4; ++rg) {
                const float v = acc[mt][nt][rg] + bv;
                if (OUT_HALF) ((half_t*)Cout)[(size_t)(m0 + rg) * N + n] = (half_t)v;
                else          ((float*) Cout)[(size_t)(m0 + rg) * N + n] = v;
            }
        }
    }
}

// ---------------------------------------------------------------------------
// RMSNorm (full 1024) + axial 2D RoPE on the f16 qkv buffer (fp32 math).
// Frame = 32 consecutive K tokens. j-assignment is PERMUTED so that the two
// QK^T 16-row C-tiles concatenate into the K=32 PV B-operand:
//   tile A row m (=quad*4+rr) <-> token off = quad*8+rr
//   tile B row m              <-> token off = quad*8+4+rr
//  - Q (scaled by 0.125*log2e, rotated) -> in place (halfs [0,1024))
//  - K -> Kf: [bh][frame][tile(2)][dt2(2)][lane(64)][8]  (4KB/frame)
//  - V -> Vf: [bh][frame][dt(4)][lane(64)][8]            (4KB/frame)
//    Vf lane = (d&15) + 16*((s&31)>>3), elem i = s&7  (A-op of K=32 PV MFMA)
// ---------------------------------------------------------------------------
__global__ __launch_bounds__(256)
void normrope_v5(half_t* __restrict__ qkvh, const float* __restrict__ q_scale,
                 const float* __restrict__ k_scale, const int* __restrict__ wptr,
                 half_t* __restrict__ Kf, half_t* __restrict__ Vf)
{
    const int token = blockIdx.x;        // b*SS + s
    const int s     = token % SS;
    const int b     = token / SS;
    const int w     = *wptr;
    const int t     = threadIdx.x;
    const float rowp = (float)(s / w);
    const float colp = (float)(s % w);

    half_t* base = qkvh + (size_t)token * 3072;

    const int frame = s >> 5;            // 0..71
    const int off   = s & 31;

    // ---- V -> Vf (A-operand stream of the K=32 PV MFMA) ----
    {
        half4 v4 = *(const half4*)(base + 2048 + 4 * t);
        const int dabs0 = 4 * t;
        const int h  = dabs0 >> 6;
        const int qv = off >> 3;         // k quad
        const int iv = off & 7;          // k elem
        half_t* vdst = Vf + ((size_t)(b * HH + h) * 72 + frame) * 2048;
        #pragma unroll
        for (int ii = 0; ii < 4; ++ii) {
            const int d = (dabs0 + ii) & 63;
            vdst[(size_t)(d >> 4) * 512 + ((d & 15) + 16 * qv) * 8 + iv] = v4[ii];
        }
    }

    __shared__ float buf[DIMC];
    __shared__ float red[4];

    // permuted j-tile coords for this token
    const int ktile = (off >> 2) & 1;               // A/B tile
    const int kmrow = ((off >> 3) << 2) + (off & 3); // row within tile

    #pragma unroll
    for (int sel = 0; sel < 2; ++sel) {
        half_t* row = base + sel * DIMC;
        const float* scp = sel ? k_scale : q_scale;

        half4 xh = *(const half4*)(row + 4 * t);
        float x0 = (float)xh[0], x1 = (float)xh[1], x2 = (float)xh[2], x3 = (float)xh[3];
        float ss = x0 * x0 + x1 * x1 + x2 * x2 + x3 * x3;
        #pragma unroll
        for (int o = 32; o >= 1; o >>= 1) ss += __shfl_xor(ss, o);
        if ((t & 63) == 0) red[t >> 6] = ss;
        __syncthreads();

        const float rinv = rsqrtf((red[0] + red[1] + red[2] + red[3]) * (1.0f / DIMC) + 1e-6f);
        float4 g = *(const float4*)(scp + 4 * t);
        buf[4 * t + 0] = x0 * rinv * g.x;
        buf[4 * t + 1] = x1 * rinv * g.y;
        buf[4 * t + 2] = x2 * rinv * g.z;
        buf[4 * t + 3] = x3 * rinv * g.w;
        __syncthreads();

        const float qsc = sel ? 1.0f : (0.125f * LOG2E);  // log2-domain scores

        #pragma unroll
        for (int pp = 0; pp < 2; ++pp) {
            const int p = t + pp * 256;
            const int h = p >> 5;
            const int r = p & 31;
            const int j = r & 15;
            const float pos = (r < 16) ? rowp : colp;
            const int d1 = (r < 16) ? j : (32 + j);   // within-head dim
            const int d2 = d1 + 16;
            // freq = 10000^(-j/16) = exp2(-j * log2(10000)/16)
            const float freq = exp2f((float)j * -0.83048202372f);
            const float ang  = pos * freq;
            float sn, cs;
            __sincosf(ang, &sn, &cs);
            const float a1 = buf[h * HD + d1], a2 = buf[h * HD + d2];
            const float o1 = (a1 * cs - a2 * sn) * qsc;
            const float o2 = (a2 * cs + a1 * sn) * qsc;
            if (sel == 0) {
                row[h * HD + d1] = (half_t)o1;
                row[h * HD + d2] = (half_t)o2;
            } else {
                half_t* kdst = Kf + ((size_t)(b * HH + h) * 72 + frame) * 2048
                             + (size_t)ktile * 1024;
                const int lq1 = (d1 & 31) >> 3, i1 = d1 & 7;
                const int lq2 = (d2 & 31) >> 3, i2 = d2 & 7;
                kdst[(size_t)(d1 >> 5) * 512 + (kmrow + 16 * lq1) * 8 + i1] = (half_t)o1;
                kdst[(size_t)(d2 >> 5) * 512 + (kmrow + 16 * lq2) * 8 + i2] = (half_t)o2;
            }
        }
        __syncthreads();   // buf/red reused by next sel
    }
}

// ---------------------------------------------------------------------------
// Flash attention v4: all-K=32 MFMA. Per frame (32 j's) per wave:
// 16 QK^T MFMAs + 16 PV MFMAs (P concatenates tile A/B regs into the K=32
// B-operand thanks to the permuted j-assignment). log2-domain softmax
// (exp2, no mul). XCD-swizzled 1D grid: each XCD owns 4 bh's so their K/V
// streams (2.3 MB) stay resident in its private L2.
// ---------------------------------------------------------------------------
__global__ __launch_bounds__(256)
void flash_attn_mfma4(const half_t* __restrict__ qkvh, const half_t* __restrict__ Kf,
                      const half_t* __restrict__ Vf, half_t* __restrict__ attn_h)
{
    const int flat = blockIdx.x;         // 0..1151
    const int xcd  = flat & 7;
    const int jj   = flat >> 3;          // 0..143
    const int bh   = xcd * 4 + (jj / 36);
    const int qtb  = jj % 36;
    const int b    = bh >> 4, h = bh & 15;
    const int t    = threadIdx.x;
    const int w    = t >> 6;
    const int lane = t & 63;
    const int l15  = lane & 15, quad = lane >> 4;

    const size_t tb = (size_t)b * SS;
    const int q0 = qtb * 64;

    // Q B-frags (loop invariant): B[k=quad*8+i][n=l15]
    half8 qf[4][2];
    #pragma unroll
    for (int qt = 0; qt < 4; ++qt)
        #pragma unroll
        for (int dt2 = 0; dt2 < 2; ++dt2)
            qf[qt][dt2] = *(const half8*)(qkvh + (tb + q0 + qt * 16 + l15) * 3072
                                          + h * HD + dt2 * 32 + quad * 8);

    f32x4 acc[4][4];                     // [dt][qt] : O^T[dt*16+quad*4+reg][qt*16+l15]
    float m_i[4], l_i[4];                // log2-domain max; lane-local l partial
    #pragma unroll
    for (int qt = 0; qt < 4; ++qt) {
        m_i[qt] = -INFINITY; l_i[qt] = 0.f;
        #pragma unroll
        for (int dt = 0; dt < 4; ++dt) acc[dt][qt] = (f32x4){0.f, 0.f, 0.f, 0.f};
    }

    const half_t* kbase = Kf + (size_t)bh * 72 * 2048;
    const half_t* vbase = Vf + (size_t)bh * 72 * 2048;

    for (int fr = w; fr < 72; fr += 4) {
        const half_t* kp = kbase + (size_t)fr * 2048;
        half8 kfA[2], kfB[2];
        kfA[0] = *(const half8*)(kp + lane * 8);
        kfA[1] = *(const half8*)(kp + 512 + lane * 8);
        kfB[0] = *(const half8*)(kp + 1024 + lane * 8);
        kfB[1] = *(const half8*)(kp + 1536 + lane * 8);

        const half_t* vp = vbase + (size_t)fr * 2048 + lane * 8;
        half8 vf[4];
        #pragma unroll
        for (int dt = 0; dt < 4; ++dt) vf[dt] = *(const half8*)(vp + dt * 512);

        // ---- S^T = K . Q^T (log2 domain; two 16-row C-tiles) ----
        f32x4 scA[4], scB[4];
        #pragma unroll
        for (int qt = 0; qt < 4; ++qt) {
            scA[qt] = (f32x4){0.f, 0.f, 0.f, 0.f};
            scB[qt] = (f32x4){0.f, 0.f, 0.f, 0.f};
            #pragma unroll
            for (int dt2 = 0; dt2 < 2; ++dt2) {
                scA[qt] = __builtin_amdgcn_mfma_f32_16x16x32_f16(
                    kfA[dt2], qf[qt][dt2], scA[qt], 0, 0, 0);
                scB[qt] = __builtin_amdgcn_mfma_f32_16x16x32_f16(
                    kfB[dt2], qf[qt][dt2], scB[qt], 0, 0, 0);
            }
        }

        // ---- online softmax: one frame per 32 j's, exp2 ----
        half8 pf[4];
        #pragma unroll
        for (int qt = 0; qt < 4; ++qt) {
            float mx = fmaxf(fmaxf(fmaxf(scA[qt][0], scA[qt][1]),
                                   fmaxf(scA[qt][2], scA[qt][3])),
                             fmaxf(fmaxf(scB[qt][0], scB[qt][1]),
                                   fmaxf(scB[qt][2], scB[qt][3])));
            mx = fmaxf(mx, __shfl_xor(mx, 16));
            mx = fmaxf(mx, __shfl_xor(mx, 32));
            if (__any(mx > m_i[qt])) {       // uniform branch: rescale needed
                const float mn = fmaxf(m_i[qt], mx);
                const float alpha = exp2f(m_i[qt] - mn);
                m_i[qt] = mn;
                l_i[qt] *= alpha;
                #pragma unroll
                for (int dt = 0; dt < 4; ++dt) acc[dt][qt] *= alpha;
            }
            const float m = m_i[qt];
            const float pA0 = exp2f(scA[qt][0] - m);
            const float pA1 = exp2f(scA[qt][1] - m);
            const float pA2 = exp2f(scA[qt][2] - m);
            const float pA3 = exp2f(scA[qt][3] - m);
            const float pB0 = exp2f(scB[qt][0] - m);
            const float pB1 = exp2f(scB[qt][1] - m);
            const float pB2 = exp2f(scB[qt][2] - m);
            const float pB3 = exp2f(scB[qt][3] - m);
            l_i[qt] += (pA0 + pA1 + pA2 + pA3) + (pB0 + pB1 + pB2 + pB3);
            pf[qt] = (half8){(half_t)pA0, (half_t)pA1, (half_t)pA2, (half_t)pA3,
                             (half_t)pB0, (half_t)pB1, (half_t)pB2, (half_t)pB3};
        }

        // ---- O^T += V^T . P^T (one K=32 MFMA per dt,qt) ----
        #pragma unroll
        for (int dt = 0; dt < 4; ++dt)
            #pragma unroll
            for (int qt = 0; qt < 4; ++qt)
                acc[dt][qt] = __builtin_amdgcn_mfma_f32_16x16x32_f16(
                    vf[dt], pf[qt], acc[dt][qt], 0, 0, 0);
    }

    // ---- merge the 4 waves' partial (m, l, O^T) ----
    __shared__ float mlb[4][64][2];
    __shared__ float Obuf[64][66];

    if (quad == 0) {
        #pragma unroll
        for (int qt = 0; qt < 4; ++qt)
            mlb[w][qt * 16 + l15][0] = m_i[qt];
    }
    #pragma unroll
    for (int qt = 0; qt < 4; ++qt) {      // reduce lane-local l across quads
        float lq = l_i[qt];
        lq += __shfl_xor(lq, 16);
        lq += __shfl_xor(lq, 32);
        if (quad == 0) mlb[w][qt * 16 + l15][1] = lq;
    }
    __syncthreads();

    float fac[4];
    #pragma unroll
    for (int qt = 0; qt < 4; ++qt) {
        const int q = qt * 16 + l15;
        const float M = fmaxf(fmaxf(mlb[0][q][0], mlb[1][q][0]),
                              fmaxf(mlb[2][q][0], mlb[3][q][0]));
        const float L = mlb[0][q][1] * exp2f(mlb[0][q][0] - M)
                      + mlb[1][q][1] * exp2f(mlb[1][q][0] - M)
                      + mlb[2][q][1] * exp2f(mlb[2][q][0] - M)
                      + mlb[3][q][1] * exp2f(mlb[3][q][0] - M);
        fac[qt] = exp2f(m_i[qt] - M) / L;
    }

    #pragma unroll
    for (int ph = 0; ph < 4; ++ph) {
        if (w == ph) {
            #pragma unroll
            for (int dt = 0; dt < 4; ++dt)
                #pragma unroll
                for (int qt = 0; qt < 4; ++qt)
                    #pragma unroll
                    for (int rg = 0; rg < 4; ++rg) {
                        const int d = dt * 16 + quad * 4 + rg;
                        const int q = qt * 16 + l15;
                        const float v = acc[dt][qt][rg] * fac[qt];
                        if (ph == 0) Obuf[d][q] = v; else Obuf[d][q] += v;
                    }
        }
        __syncthreads();
    }

    // ---- store O as f16, tile-blocked [mb][kb][128][32] for the proj GEMM ----
    {
        const int q  = t >> 2;               // token within q-tile
        const int ds = (t & 3) * 16;
        const size_t mrow = tb + q0 + q;
        const int mb2 = (int)(mrow >> 7);
        const int mm  = (int)(mrow & 127);
        #pragma unroll
        for (int g = 0; g < 4; ++g) {
            const int dd = ds + 4 * g;
            const int kb2 = (h * HD + dd) >> 5;
            const int kk  = dd & 31;
            half4 o;
            o[0] = (half_t)Obuf[dd + 0][q];
            o[1] = (half_t)Obuf[dd + 1][q];
            o[2] = (half_t)Obuf[dd + 2][q];
            o[3] = (half_t)Obuf[dd + 3][q];
            *(half4*)(attn_h + ((size_t)mb2 * 32 + kb2) * 4096 + mm * 32 + kk) = o;
        }
    }
}

// ---------------------------------------------------------------------------
// Launch
// ---------------------------------------------------------------------------
extern "C" void kernel_launch(void* const* d_in, const int* in_sizes, int n_in,
                              void* d_out, int out_size, void* d_ws, size_t ws_size,
                              hipStream_t stream)
{
    const float* input   = (const float*)d_in[0];
    const float* qkv_w   = (const float*)d_in[1];
    const float* qkv_b   = (const float*)d_in[2];
    const float* q_scale = (const float*)d_in[3];
    const float* k_scale = (const float*)d_in[4];
    const float* proj_w  = (const float*)d_in[5];
    const float* proj_b  = (const float*)d_in[6];
    const int*   width   = (const int*)d_in[8];
    float* out = (float*)d_out;

    // ws layout (all f16): qkv_h 28.3MB | attn_h 9.4 | Vf 9.4 | Ah 9.4 (reused
    // as Kf after GEMM1) | Bh1 6.3 | Bh2 2.1  => 65.0 MB total
    half_t* qkvh   = (half_t*)d_ws;
    half_t* attn_h = qkvh   + (size_t)4608 * 3072;
    half_t* Vf     = attn_h + (size_t)4608 * 1024;
    half_t* Ah     = Vf     + (size_t)32 * 72 * 2048;
    half_t* Bh1    = Ah     + (size_t)4608 * 1024;
    half_t* Bh2    = Bh1    + (size_t)3072 * 1024;
    half_t* Kf     = Ah;    // Ah is dead after GEMM1; Kf is written by normrope

    const int M = BB * SS;   // 4608

    // 0) fp32 -> f16 tile-blocked converters (proj_w 64-row-blocked)
    convert_tile_f16<128><<<dim3(M / 128, DINC / 32),        256, 0, stream>>>(input,  Ah,  DINC);
    convert_tile_f16<128><<<dim3(3 * DIMC / 128, DINC / 32), 256, 0, stream>>>(qkv_w, Bh1, DINC);
    convert_tile_f16<64><<<dim3(DINC / 64, DIMC / 32),       256, 0, stream>>>(proj_w, Bh2, DIMC);

    // 1) qkv_h = f16( input @ qkv_w^T + qkv_b )
    gemm_mfma<128, true><<<dim3(3 * DIMC / 128, M / 128), 256, 0, stream>>>(
        Ah, Bh1, qkv_b, qkvh, M, 3 * DIMC, DINC);

    // 2) RMSNorm + RoPE: Q in place (log2-scaled), K -> Kf, V -> Vf
    normrope_v5<<<M, 256, 0, stream>>>(qkvh, q_scale, k_scale, width, Kf, Vf);

    // 3) MFMA flash attention -> attn_h (f16, tile-blocked), XCD-swizzled
    flash_attn_mfma4<<<dim3(SS / 64 * BB * HH), 256, 0, stream>>>(qkvh, Kf, Vf, attn_h);

    // 4) out = attn @ proj_w^T + proj_b  (fp32 out, BN=64 for occupancy)
    gemm_mfma<64, false><<<dim3(DINC / 64, M / 128), 256, 0, stream>>>(
        attn_h, Bh2, proj_b, out, M, DINC, DIMC);
}

// Round 7
// 275.105 us; speedup vs baseline: 1.1303x; 1.1303x over previous
//
#include <hip/hip_runtime.h>
#include <math.h>

// Problem constants (fixed by the reference)
#define BB   2
#define SS   2304
#define DINC 1024
#define DIMC 1024
#define HH   16
#define HD   64

typedef _Float16 half_t;
typedef __attribute__((ext_vector_type(4))) _Float16 half4;   // 2 VGPRs
typedef __attribute__((ext_vector_type(8))) _Float16 half8;   // 4 VGPRs
typedef __attribute__((ext_vector_type(4))) float    f32x4;   // 4 VGPRs

#define LOG2E 1.44269504088896340736f
#define EXP2(x) __builtin_amdgcn_exp2f(x)     // raw v_exp_f32, no libm guard path

__device__ __forceinline__ half4 lo4(half8 x) { return (half4){x[0], x[1], x[2], x[3]}; }
__device__ __forceinline__ half4 hi4(half8 x) { return (half4){x[4], x[5], x[6], x[7]}; }

// async global->LDS, 16B per lane; LDS dest = wave-uniform base + lane*16
#define GLOAD_LDS16(gp, lp)                                                     \
    __builtin_amdgcn_global_load_lds(                                           \
        (const __attribute__((address_space(1))) void*)(gp),                    \
        (__attribute__((address_space(3))) void*)(lp), 16, 0, 0)

// ---------------------------------------------------------------------------
// Converter: fp32 row-major [R][K] -> f16 tile-blocked [R/RB][K/32][RB][32].
// ---------------------------------------------------------------------------
template<int RB>
__global__ __launch_bounds__(256)
void convert_tile_f16(const float* __restrict__ src, half_t* __restrict__ dst, int K)
{
    constexpr int EPT = RB * 32 / 256;       // elements per thread (16 or 8)
    const int mb = blockIdx.x;
    const int kb = blockIdx.y;
    const int t  = threadIdx.x;
    const int e0 = t * EPT;
    const int mm = e0 >> 5;
    const int kk = e0 & 31;
    const float* sp = src + (size_t)(mb * RB + mm) * K + kb * 32 + kk;
    half_t*      dp = dst + ((size_t)mb * (K >> 5) + kb) * (RB * 32) + mm * 32 + kk;
    #pragma unroll
    for (int g = 0; g < EPT / 4; ++g) {
        float4 v = *(const float4*)(sp + 4 * g);
        dp[4 * g + 0] = (half_t)v.x; dp[4 * g + 1] = (half_t)v.y;
        dp[4 * g + 2] = (half_t)v.z; dp[4 * g + 3] = (half_t)v.w;
    }
}

// ---------------------------------------------------------------------------
// f16 MFMA GEMM (NT): C[m][n] = sum_k A[m][k]*W[n][k] + bias[n], fp32 accum.
// (unchanged from round 6)
// ---------------------------------------------------------------------------
template<int BN, bool OUT_HALF>
__global__ __launch_bounds__(256)
void gemm_mfma(const half_t* __restrict__ Ah, const half_t* __restrict__ Bh,
               const float* __restrict__ bias, void* __restrict__ Cout,
               int M, int N, int K)
{
    constexpr int MT = (BN == 128) ? 4 : 2;
    constexpr int NT = 4;
    const int KB = K >> 5;
    __shared__ half_t As[8192];          // [u][128][32]
    __shared__ half_t Bs[2 * BN * 32];   // [u][BN][32]

    const int t    = threadIdx.x;
    const int w    = t >> 6;
    const int lane = t & 63;
    const int l15  = lane & 15, quad = lane >> 4;
    const int wr   = (BN == 128) ? (w >> 1) : w;
    const int wc   = (BN == 128) ? (w & 1) : 0;
    const int mb   = blockIdx.y, nb = blockIdx.x;

    f32x4 acc[MT][NT];
    #pragma unroll
    for (int mt = 0; mt < MT; ++mt)
        #pragma unroll
        for (int nt = 0; nt < NT; ++nt) acc[mt][nt] = (f32x4){0.f, 0.f, 0.f, 0.f};

    const half_t* atile = Ah + (size_t)mb * KB * 4096;
    const half_t* btile = Bh + (size_t)nb * KB * (BN * 32);

    for (int kb = 0; kb < KB; kb += 2) {
        #pragma unroll
        for (int u = 0; u < 2; ++u) {
            const half_t* at = atile + (size_t)(kb + u) * 4096;
            const half_t* bt = btile + (size_t)(kb + u) * (BN * 32);
            #pragma unroll
            for (int v = 0; v < 2; ++v) {
                const int ch = w * 2 + v;
                GLOAD_LDS16(at + ch * 512 + lane * 8, As + u * 4096 + ch * 512);
            }
            if (BN == 128) {
                #pragma unroll
                for (int v = 0; v < 2; ++v) {
                    const int ch = w * 2 + v;
                    GLOAD_LDS16(bt + ch * 512 + lane * 8, Bs + u * 4096 + ch * 512);
                }
            } else {
                GLOAD_LDS16(bt + w * 512 + lane * 8, Bs + u * (BN * 32) + w * 512);
            }
        }
        __syncthreads();

        #pragma unroll
        for (int u = 0; u < 2; ++u) {
            half8 af[MT], bf[NT];
            #pragma unroll
            for (int mt = 0; mt < MT; ++mt)
                af[mt] = *(const half8*)(As + u * 4096
                                         + (wr * (MT * 16) + mt * 16 + l15) * 32 + quad * 8);
            #pragma unroll
            for (int nt = 0; nt < NT; ++nt)
                bf[nt] = *(const half8*)(Bs + u * (BN * 32)
                                         + (wc * 64 + nt * 16 + l15) * 32 + quad * 8);
            #pragma unroll
            for (int mt = 0; mt < MT; ++mt)
                #pragma unroll
                for (int nt = 0; nt < NT; ++nt)
                    acc[mt][nt] = __builtin_amdgcn_mfma_f32_16x16x32_f16(
                        af[mt], bf[nt], acc[mt][nt], 0, 0, 0);
        }
        __syncthreads();
    }

    const int bm = mb * 128, bn = nb * BN;
    #pragma unroll
    for (int nt = 0; nt < NT; ++nt) {
        const int n  = bn + wc * 64 + nt * 16 + l15;
        const float bv = bias[n];
        #pragma unroll
        for (int mt = 0; mt < MT; ++mt) {
            const int m0 = bm + wr * (MT * 16) + mt * 16 + quad * 4;
            #pragma unroll
            for (int rg = 0; rg < 4; ++rg) {
                const float v = acc[mt][nt][rg] + bv;
                if (OUT_HALF) ((half_t*)Cout)[(size_t)(m0 + rg) * N + n] = (half_t)v;
                else          ((float*) Cout)[(size_t)(m0 + rg) * N + n] = v;
            }
        }
    }
}

// ---------------------------------------------------------------------------
// RMSNorm (full 1024) + axial 2D RoPE on the f16 qkv buffer (fp32 math).
// Frame = 32 consecutive K tokens = 2 j-tiles of 16.
//  - Q (scaled by 0.125*log2e, rotated) -> in place (halfs [0,1024))
//  - K -> Kf: [bh][fr][jt(2)][dt2(2)][lane(64)][8]     (4KB/frame)
//      token s: jt=(s>>4)&1, m=s&15; dim d: dt2=d>>5, kq=(d&31)>>3, i=d&7
//      lane = m + 16*kq   (A-operand of 16x16x32 QK^T MFMA)
//  - V -> Vf: [bh][fr][jt(2)][dp(2)][lane(64)][8]      (4KB/frame)
//      token s: j16=s&15 -> vq=j16>>2, vi=j16&3; dim d: dt=d>>4, dp=dt>>1,
//      par=dt&1, m=d&15; lane = m + 16*vq, half-elem = par*4+vi
//      (half8 read gives dt=2dp in lo4, dt=2dp+1 in hi4; K=16 PV A-operand)
// ---------------------------------------------------------------------------
__global__ __launch_bounds__(256)
void normrope_v6(half_t* __restrict__ qkvh, const float* __restrict__ q_scale,
                 const float* __restrict__ k_scale, const int* __restrict__ wptr,
                 half_t* __restrict__ Kf, half_t* __restrict__ Vf)
{
    const int token = blockIdx.x;        // b*SS + s
    const int s     = token % SS;
    const int b     = token / SS;
    const int w     = *wptr;
    const int t     = threadIdx.x;
    const float rowp = (float)(s / w);
    const float colp = (float)(s % w);

    half_t* base = qkvh + (size_t)token * 3072;

    const int fr = s >> 5;
    const int jt = (s >> 4) & 1;

    // ---- V -> Vf ----
    {
        half4 v4 = *(const half4*)(base + 2048 + 4 * t);
        const int dabs0 = 4 * t;
        const int h  = dabs0 >> 6;
        const int vq = (s & 15) >> 2;
        const int vi = s & 3;
        half_t* vdst = Vf + ((size_t)(b * HH + h) * 72 + fr) * 2048 + jt * 1024;
        #pragma unroll
        for (int ii = 0; ii < 4; ++ii) {
            const int d   = (dabs0 + ii) & 63;
            const int dt  = d >> 4;
            vdst[(size_t)(dt >> 1) * 512 + ((d & 15) + 16 * vq) * 8 + (dt & 1) * 4 + vi]
                = v4[ii];
        }
    }

    __shared__ float buf[DIMC];
    __shared__ float red[4];

    const int km = s & 15;               // token's row within its j-tile

    #pragma unroll
    for (int sel = 0; sel < 2; ++sel) {
        half_t* row = base + sel * DIMC;
        const float* scp = sel ? k_scale : q_scale;

        half4 xh = *(const half4*)(row + 4 * t);
        float x0 = (float)xh[0], x1 = (float)xh[1], x2 = (float)xh[2], x3 = (float)xh[3];
        float ss = x0 * x0 + x1 * x1 + x2 * x2 + x3 * x3;
        #pragma unroll
        for (int o = 32; o >= 1; o >>= 1) ss += __shfl_xor(ss, o);
        if ((t & 63) == 0) red[t >> 6] = ss;
        __syncthreads();

        const float rinv = rsqrtf((red[0] + red[1] + red[2] + red[3]) * (1.0f / DIMC) + 1e-6f);
        float4 g = *(const float4*)(scp + 4 * t);
        buf[4 * t + 0] = x0 * rinv * g.x;
        buf[4 * t + 1] = x1 * rinv * g.y;
        buf[4 * t + 2] = x2 * rinv * g.z;
        buf[4 * t + 3] = x3 * rinv * g.w;
        __syncthreads();

        const float qsc = sel ? 1.0f : (0.125f * LOG2E);  // log2-domain scores

        #pragma unroll
        for (int pp = 0; pp < 2; ++pp) {
            const int p = t + pp * 256;
            const int h = p >> 5;
            const int r = p & 31;
            const int j = r & 15;
            const float pos = (r < 16) ? rowp : colp;
            const int d1 = (r < 16) ? j : (32 + j);   // within-head dim
            const int d2 = d1 + 16;
            const float freq = exp2f((float)j * -0.83048202372f);
            const float ang  = pos * freq;
            float sn, cs;
            __sincosf(ang, &sn, &cs);
            const float a1 = buf[h * HD + d1], a2 = buf[h * HD + d2];
            const float o1 = (a1 * cs - a2 * sn) * qsc;
            const float o2 = (a2 * cs + a1 * sn) * qsc;
            if (sel == 0) {
                row[h * HD + d1] = (half_t)o1;
                row[h * HD + d2] = (half_t)o2;
            } else {
                half_t* kdst = Kf + ((size_t)(b * HH + h) * 72 + fr) * 2048 + jt * 1024;
                kdst[(size_t)(d1 >> 5) * 512 + (km + 16 * ((d1 & 31) >> 3)) * 8 + (d1 & 7)]
                    = (half_t)o1;
                kdst[(size_t)(d2 >> 5) * 512 + (km + 16 * ((d2 & 31) >> 3)) * 8 + (d2 & 7)]
                    = (half_t)o2;
            }
        }
        __syncthreads();   // buf/red reused by next sel
    }
}

// ---------------------------------------------------------------------------
// Flash attention v5: occupancy-first. Wave w owns (j-tile jt=w&1 of each
// frame, q-half qh=w>>1) -> acc is only 32 AGPRs, ~110 regs total, 4
// waves/SIMD via __launch_bounds__(256,4). K/V frames (8KB) staged once per
// block into double-buffered LDS with global_load_lds, prefetched one frame
// ahead (the per-frame barrier drains the async loads). log2-domain online
// softmax with raw v_exp_f32. Epilogue: 2-way merge (same-qh wave pairs),
// Obuf overlays the retired K/V LDS.
// ---------------------------------------------------------------------------
__global__ __launch_bounds__(256, 4)
void flash_attn_mfma5(const half_t* __restrict__ qkvh, const half_t* __restrict__ Kf,
                      const half_t* __restrict__ Vf, half_t* __restrict__ attn_h)
{
    const int flat = blockIdx.x;         // 0..1151, XCD-swizzled
    const int xcd  = flat & 7;
    const int jj   = flat >> 3;          // 0..143
    const int bh   = xcd * 4 + (jj / 36);
    const int qtb  = jj % 36;
    const int b    = bh >> 4, h = bh & 15;
    const int t    = threadIdx.x;
    const int w    = t >> 6;
    const int jt   = w & 1;              // wave's j-tile within each frame
    const int qh   = w >> 1;             // wave's q-half (32 q rows)
    const int lane = t & 63;
    const int l15  = lane & 15, quad = lane >> 4;

    const size_t tb = (size_t)b * SS;
    const int q0 = qtb * 64;

    __shared__ half_t KV[2][4096];       // [buf][ K 2048 | V 2048 ] halfs (16KB)
    __shared__ float  mlb[4][32][2];     // per-wave (m, l) for its 32 q's

    // Q B-frags (loop invariant): B[k=quad*8+i][n=l15], 2 q-tiles of this q-half
    half8 qf[2][2];
    #pragma unroll
    for (int qt = 0; qt < 2; ++qt)
        #pragma unroll
        for (int dt2 = 0; dt2 < 2; ++dt2)
            qf[qt][dt2] = *(const half8*)(qkvh + (tb + q0 + qh * 32 + qt * 16 + l15) * 3072
                                          + h * HD + dt2 * 32 + quad * 8);

    f32x4 acc[4][2];                     // [dt][qt] : O^T[dt*16+quad*4+reg][q]
    float m_i[2], l_i[2];
    #pragma unroll
    for (int qt = 0; qt < 2; ++qt) {
        m_i[qt] = -INFINITY; l_i[qt] = 0.f;
        #pragma unroll
        for (int dt = 0; dt < 4; ++dt) acc[dt][qt] = (f32x4){0.f, 0.f, 0.f, 0.f};
    }

    const half_t* kbase = Kf + (size_t)bh * 72 * 2048;
    const half_t* vbase = Vf + (size_t)bh * 72 * 2048;

    // stage frame 0 into buffer 0 (each wave stages 1KB of K and 1KB of V)
    GLOAD_LDS16(kbase + w * 512 + lane * 8, &KV[0][0]    + w * 512);
    GLOAD_LDS16(vbase + w * 512 + lane * 8, &KV[0][2048] + w * 512);

    for (int fr = 0; fr < 72; ++fr) {
        const int cur = fr & 1;
        __syncthreads();                 // staged data visible; prev buffer free
        if (fr + 1 < 72) {               // prefetch next frame into other buffer
            const half_t* kg = kbase + (size_t)(fr + 1) * 2048;
            const half_t* vg = vbase + (size_t)(fr + 1) * 2048;
            GLOAD_LDS16(kg + w * 512 + lane * 8, &KV[cur ^ 1][0]    + w * 512);
            GLOAD_LDS16(vg + w * 512 + lane * 8, &KV[cur ^ 1][2048] + w * 512);
        }

        // ---- fragments from LDS (wave's j-tile only) ----
        const half_t* kb = &KV[cur][jt * 1024];
        half8 kf0 = *(const half8*)(kb + lane * 8);
        half8 kf1 = *(const half8*)(kb + 512 + lane * 8);
        const half_t* vb = &KV[cur][2048 + jt * 1024];
        half8 v01 = *(const half8*)(vb + lane * 8);
        half8 v23 = *(const half8*)(vb + 512 + lane * 8);
        half4 vf[4] = {lo4(v01), hi4(v01), lo4(v23), hi4(v23)};

        // ---- S^T = K . Q^T (16 j x 32 q, log2 domain) ----
        f32x4 sc[2];
        #pragma unroll
        for (int qt = 0; qt < 2; ++qt) {
            sc[qt] = (f32x4){0.f, 0.f, 0.f, 0.f};
            sc[qt] = __builtin_amdgcn_mfma_f32_16x16x32_f16(kf0, qf[qt][0], sc[qt], 0, 0, 0);
            sc[qt] = __builtin_amdgcn_mfma_f32_16x16x32_f16(kf1, qf[qt][1], sc[qt], 0, 0, 0);
        }

        // ---- online softmax ----
        half4 pf[2];
        #pragma unroll
        for (int qt = 0; qt < 2; ++qt) {
            float mx = fmaxf(fmaxf(sc[qt][0], sc[qt][1]), fmaxf(sc[qt][2], sc[qt][3]));
            mx = fmaxf(mx, __shfl_xor(mx, 16));
            mx = fmaxf(mx, __shfl_xor(mx, 32));
            if (__any(mx > m_i[qt])) {
                const float mn = fmaxf(m_i[qt], mx);
                const float alpha = EXP2(m_i[qt] - mn);
                m_i[qt] = mn;
                l_i[qt] *= alpha;
                #pragma unroll
                for (int dt = 0; dt < 4; ++dt) acc[dt][qt] *= alpha;
            }
            const float m = m_i[qt];
            const float p0 = EXP2(sc[qt][0] - m);
            const float p1 = EXP2(sc[qt][1] - m);
            const float p2 = EXP2(sc[qt][2] - m);
            const float p3 = EXP2(sc[qt][3] - m);
            l_i[qt] += (p0 + p1) + (p2 + p3);
            pf[qt] = (half4){(half_t)p0, (half_t)p1, (half_t)p2, (half_t)p3};
        }

        // ---- O^T += V^T . P^T (K=16) ----
        #pragma unroll
        for (int dt = 0; dt < 4; ++dt)
            #pragma unroll
            for (int qt = 0; qt < 2; ++qt)
                acc[dt][qt] = __builtin_amdgcn_mfma_f32_16x16x16f16(
                    vf[dt], pf[qt], acc[dt][qt], 0, 0, 0);
    }

    // ---- 2-way merge: waves (jt=0,jt=1) of the same q-half ----
    #pragma unroll
    for (int qt = 0; qt < 2; ++qt) {      // cross-quad reduce lane-local l
        float lq = l_i[qt];
        lq += __shfl_xor(lq, 16);
        lq += __shfl_xor(lq, 32);
        if (quad == 0) {
            mlb[w][qt * 16 + l15][0] = m_i[qt];
            mlb[w][qt * 16 + l15][1] = lq;
        }
    }
    __syncthreads();

    float fac[2];
    #pragma unroll
    for (int qt = 0; qt < 2; ++qt) {
        const int q = qt * 16 + l15;
        const float m0 = mlb[qh * 2 + 0][q][0], m1 = mlb[qh * 2 + 1][q][0];
        const float M  = fmaxf(m0, m1);
        const float L  = mlb[qh * 2 + 0][q][1] * EXP2(m0 - M)
                       + mlb[qh * 2 + 1][q][1] * EXP2(m1 - M);
        fac[qt] = EXP2(m_i[qt] - M) / L;
    }

    // Obuf overlays the retired K/V double buffer: [qh][d(64)][q(32)] fp32
    float* Ob = (float*)KV;
    #pragma unroll
    for (int ph = 0; ph < 2; ++ph) {
        if (jt == ph) {
            #pragma unroll
            for (int dt = 0; dt < 4; ++dt)
                #pragma unroll
                for (int qt = 0; qt < 2; ++qt)
                    #pragma unroll
                    for (int rg = 0; rg < 4; ++rg) {
                        const int d = dt * 16 + quad * 4 + rg;
                        const int q = qt * 16 + l15;
                        const float v = acc[dt][qt][rg] * fac[qt];
                        if (ph == 0) Ob[qh * 2048 + d * 32 + q] = v;
                        else         Ob[qh * 2048 + d * 32 + q] += v;
                    }
        }
        __syncthreads();
    }

    // ---- store O as f16, tile-blocked [mb][kb][128][32] for the proj GEMM ----
    {
        const int q   = t >> 2;              // token within q-tile (0..63)
        const int ds  = (t & 3) * 16;
        const int qh2 = q >> 5, qq = q & 31;
        const size_t mrow = tb + q0 + q;
        const int mb2 = (int)(mrow >> 7);
        const int mm  = (int)(mrow & 127);
        #pragma unroll
        for (int g = 0; g < 4; ++g) {
            const int dd = ds + 4 * g;
            const int kb2 = (h * HD + dd) >> 5;
            const int kk  = dd & 31;
            half4 o;
            o[0] = (half_t)Ob[qh2 * 2048 + (dd + 0) * 32 + qq];
            o[1] = (half_t)Ob[qh2 * 2048 + (dd + 1) * 32 + qq];
            o[2] = (half_t)Ob[qh2 * 2048 + (dd + 2) * 32 + qq];
            o[3] = (half_t)Ob[qh2 * 2048 + (dd + 3) * 32 + qq];
            *(half4*)(attn_h + ((size_t)mb2 * 32 + kb2) * 4096 + mm * 32 + kk) = o;
        }
    }
}

// ---------------------------------------------------------------------------
// Launch
// ---------------------------------------------------------------------------
extern "C" void kernel_launch(void* const* d_in, const int* in_sizes, int n_in,
                              void* d_out, int out_size, void* d_ws, size_t ws_size,
                              hipStream_t stream)
{
    const float* input   = (const float*)d_in[0];
    const float* qkv_w   = (const float*)d_in[1];
    const float* qkv_b   = (const float*)d_in[2];
    const float* q_scale = (const float*)d_in[3];
    const float* k_scale = (const float*)d_in[4];
    const float* proj_w  = (const float*)d_in[5];
    const float* proj_b  = (const float*)d_in[6];
    const int*   width   = (const int*)d_in[8];
    float* out = (float*)d_out;

    // ws layout (all f16): qkv_h 28.3MB | attn_h 9.4 | Vf 9.4 | Ah 9.4 (reused
    // as Kf after GEMM1) | Bh1 6.3 | Bh2 2.1  => 65.0 MB total
    half_t* qkvh   = (half_t*)d_ws;
    half_t* attn_h = qkvh   + (size_t)4608 * 3072;
    half_t* Vf     = attn_h + (size_t)4608 * 1024;
    half_t* Ah     = Vf     + (size_t)32 * 72 * 2048;
    half_t* Bh1    = Ah     + (size_t)4608 * 1024;
    half_t* Bh2    = Bh1    + (size_t)3072 * 1024;
    half_t* Kf     = Ah;    // Ah is dead after GEMM1; Kf is written by normrope

    const int M = BB * SS;   // 4608

    // 0) fp32 -> f16 tile-blocked converters (proj_w 64-row-blocked)
    convert_tile_f16<128><<<dim3(M / 128, DINC / 32),        256, 0, stream>>>(input,  Ah,  DINC);
    convert_tile_f16<128><<<dim3(3 * DIMC / 128, DINC / 32), 256, 0, stream>>>(qkv_w, Bh1, DINC);
    convert_tile_f16<64><<<dim3(DINC / 64, DIMC / 32),       256, 0, stream>>>(proj_w, Bh2, DIMC);

    // 1) qkv_h = f16( input @ qkv_w^T + qkv_b )
    gemm_mfma<128, true><<<dim3(3 * DIMC / 128, M / 128), 256, 0, stream>>>(
        Ah, Bh1, qkv_b, qkvh, M, 3 * DIMC, DINC);

    // 2) RMSNorm + RoPE: Q in place (log2-scaled), K -> Kf, V -> Vf
    normrope_v6<<<M, 256, 0, stream>>>(qkvh, q_scale, k_scale, width, Kf, Vf);

    // 3) MFMA flash attention -> attn_h (f16, tile-blocked), XCD-swizzled
    flash_attn_mfma5<<<dim3(SS / 64 * BB * HH), 256, 0, stream>>>(qkvh, Kf, Vf, attn_h);

    // 4) out = attn @ proj_w^T + proj_b  (fp32 out, BN=64 for occupancy)
    gemm_mfma<64, false><<<dim3(DINC / 64, M / 128), 256, 0, stream>>>(
        attn_h, Bh2, proj_b, out, M, DINC, DIMC);
}

// Round 8
// 270.996 us; speedup vs baseline: 1.1475x; 1.0152x over previous
//
#include <hip/hip_runtime.h>
#include <math.h>

// Problem constants (fixed by the reference)
#define BB   2
#define SS   2304
#define DINC 1024
#define DIMC 1024
#define HH   16
#define HD   64

typedef _Float16 half_t;
typedef __attribute__((ext_vector_type(4))) _Float16 half4;   // 2 VGPRs
typedef __attribute__((ext_vector_type(8))) _Float16 half8;   // 4 VGPRs
typedef __attribute__((ext_vector_type(4))) float    f32x4;   // 4 VGPRs

#define LOG2E 1.44269504088896340736f
#define EXP2(x) __builtin_amdgcn_exp2f(x)     // raw v_exp_f32, no libm guard path

__device__ __forceinline__ half4 lo4(half8 x) { return (half4){x[0], x[1], x[2], x[3]}; }
__device__ __forceinline__ half4 hi4(half8 x) { return (half4){x[4], x[5], x[6], x[7]}; }

// async global->LDS, 16B per lane; LDS dest = wave-uniform base + lane*16
#define GLOAD_LDS16(gp, lp)                                                     \
    __builtin_amdgcn_global_load_lds(                                           \
        (const __attribute__((address_space(1))) void*)(gp),                    \
        (__attribute__((address_space(3))) void*)(lp), 16, 0, 0)

// ---------------------------------------------------------------------------
// Converter: fp32 row-major [R][K] -> f16 tile-blocked [R/RB][K/32][RB][32].
// ---------------------------------------------------------------------------
template<int RB>
__global__ __launch_bounds__(256)
void convert_tile_f16(const float* __restrict__ src, half_t* __restrict__ dst, int K)
{
    constexpr int EPT = RB * 32 / 256;       // elements per thread (16 or 8)
    const int mb = blockIdx.x;
    const int kb = blockIdx.y;
    const int t  = threadIdx.x;
    const int e0 = t * EPT;
    const int mm = e0 >> 5;
    const int kk = e0 & 31;
    const float* sp = src + (size_t)(mb * RB + mm) * K + kb * 32 + kk;
    half_t*      dp = dst + ((size_t)mb * (K >> 5) + kb) * (RB * 32) + mm * 32 + kk;
    #pragma unroll
    for (int g = 0; g < EPT / 4; ++g) {
        float4 v = *(const float4*)(sp + 4 * g);
        dp[4 * g + 0] = (half_t)v.x; dp[4 * g + 1] = (half_t)v.y;
        dp[4 * g + 2] = (half_t)v.z; dp[4 * g + 3] = (half_t)v.w;
    }
}

// ---------------------------------------------------------------------------
// f16 MFMA GEMM (NT): C[m][n] = sum_k A[m][k]*W[n][k] + bias[n], fp32 accum.
// (unchanged from round 7)
// ---------------------------------------------------------------------------
template<int BN, bool OUT_HALF>
__global__ __launch_bounds__(256)
void gemm_mfma(const half_t* __restrict__ Ah, const half_t* __restrict__ Bh,
               const float* __restrict__ bias, void* __restrict__ Cout,
               int M, int N, int K)
{
    constexpr int MT = (BN == 128) ? 4 : 2;
    constexpr int NT = 4;
    const int KB = K >> 5;
    __shared__ half_t As[8192];          // [u][128][32]
    __shared__ half_t Bs[2 * BN * 32];   // [u][BN][32]

    const int t    = threadIdx.x;
    const int w    = t >> 6;
    const int lane = t & 63;
    const int l15  = lane & 15, quad = lane >> 4;
    const int wr   = (BN == 128) ? (w >> 1) : w;
    const int wc   = (BN == 128) ? (w & 1) : 0;
    const int mb   = blockIdx.y, nb = blockIdx.x;

    f32x4 acc[MT][NT];
    #pragma unroll
    for (int mt = 0; mt < MT; ++mt)
        #pragma unroll
        for (int nt = 0; nt < NT; ++nt) acc[mt][nt] = (f32x4){0.f, 0.f, 0.f, 0.f};

    const half_t* atile = Ah + (size_t)mb * KB * 4096;
    const half_t* btile = Bh + (size_t)nb * KB * (BN * 32);

    for (int kb = 0; kb < KB; kb += 2) {
        #pragma unroll
        for (int u = 0; u < 2; ++u) {
            const half_t* at = atile + (size_t)(kb + u) * 4096;
            const half_t* bt = btile + (size_t)(kb + u) * (BN * 32);
            #pragma unroll
            for (int v = 0; v < 2; ++v) {
                const int ch = w * 2 + v;
                GLOAD_LDS16(at + ch * 512 + lane * 8, As + u * 4096 + ch * 512);
            }
            if (BN == 128) {
                #pragma unroll
                for (int v = 0; v < 2; ++v) {
                    const int ch = w * 2 + v;
                    GLOAD_LDS16(bt + ch * 512 + lane * 8, Bs + u * 4096 + ch * 512);
                }
            } else {
                GLOAD_LDS16(bt + w * 512 + lane * 8, Bs + u * (BN * 32) + w * 512);
            }
        }
        __syncthreads();

        #pragma unroll
        for (int u = 0; u < 2; ++u) {
            half8 af[MT], bf[NT];
            #pragma unroll
            for (int mt = 0; mt < MT; ++mt)
                af[mt] = *(const half8*)(As + u * 4096
                                         + (wr * (MT * 16) + mt * 16 + l15) * 32 + quad * 8);
            #pragma unroll
            for (int nt = 0; nt < NT; ++nt)
                bf[nt] = *(const half8*)(Bs + u * (BN * 32)
                                         + (wc * 64 + nt * 16 + l15) * 32 + quad * 8);
            #pragma unroll
            for (int mt = 0; mt < MT; ++mt)
                #pragma unroll
                for (int nt = 0; nt < NT; ++nt)
                    acc[mt][nt] = __builtin_amdgcn_mfma_f32_16x16x32_f16(
                        af[mt], bf[nt], acc[mt][nt], 0, 0, 0);
        }
        __syncthreads();
    }

    const int bm = mb * 128, bn = nb * BN;
    #pragma unroll
    for (int nt = 0; nt < NT; ++nt) {
        const int n  = bn + wc * 64 + nt * 16 + l15;
        const float bv = bias[n];
        #pragma unroll
        for (int mt = 0; mt < MT; ++mt) {
            const int m0 = bm + wr * (MT * 16) + mt * 16 + quad * 4;
            #pragma unroll
            for (int rg = 0; rg < 4; ++rg) {
                const float v = acc[mt][nt][rg] + bv;
                if (OUT_HALF) ((half_t*)Cout)[(size_t)(m0 + rg) * N + n] = (half_t)v;
                else          ((float*) Cout)[(size_t)(m0 + rg) * N + n] = v;
            }
        }
    }
}

// ---------------------------------------------------------------------------
// RMSNorm (full 1024) + axial 2D RoPE on the f16 qkv buffer (fp32 math).
// (unchanged from round 7; Kf/Vf fragment-stream layouts per comments)
// ---------------------------------------------------------------------------
__global__ __launch_bounds__(256)
void normrope_v6(half_t* __restrict__ qkvh, const float* __restrict__ q_scale,
                 const float* __restrict__ k_scale, const int* __restrict__ wptr,
                 half_t* __restrict__ Kf, half_t* __restrict__ Vf)
{
    const int token = blockIdx.x;        // b*SS + s
    const int s     = token % SS;
    const int b     = token / SS;
    const int w     = *wptr;
    const int t     = threadIdx.x;
    const float rowp = (float)(s / w);
    const float colp = (float)(s % w);

    half_t* base = qkvh + (size_t)token * 3072;

    const int fr = s >> 5;
    const int jt = (s >> 4) & 1;

    // ---- V -> Vf ----
    {
        half4 v4 = *(const half4*)(base + 2048 + 4 * t);
        const int dabs0 = 4 * t;
        const int h  = dabs0 >> 6;
        const int vq = (s & 15) >> 2;
        const int vi = s & 3;
        half_t* vdst = Vf + ((size_t)(b * HH + h) * 72 + fr) * 2048 + jt * 1024;
        #pragma unroll
        for (int ii = 0; ii < 4; ++ii) {
            const int d   = (dabs0 + ii) & 63;
            const int dt  = d >> 4;
            vdst[(size_t)(dt >> 1) * 512 + ((d & 15) + 16 * vq) * 8 + (dt & 1) * 4 + vi]
                = v4[ii];
        }
    }

    __shared__ float buf[DIMC];
    __shared__ float red[4];

    const int km = s & 15;               // token's row within its j-tile

    #pragma unroll
    for (int sel = 0; sel < 2; ++sel) {
        half_t* row = base + sel * DIMC;
        const float* scp = sel ? k_scale : q_scale;

        half4 xh = *(const half4*)(row + 4 * t);
        float x0 = (float)xh[0], x1 = (float)xh[1], x2 = (float)xh[2], x3 = (float)xh[3];
        float ss = x0 * x0 + x1 * x1 + x2 * x2 + x3 * x3;
        #pragma unroll
        for (int o = 32; o >= 1; o >>= 1) ss += __shfl_xor(ss, o);
        if ((t & 63) == 0) red[t >> 6] = ss;
        __syncthreads();

        const float rinv = rsqrtf((red[0] + red[1] + red[2] + red[3]) * (1.0f / DIMC) + 1e-6f);
        float4 g = *(const float4*)(scp + 4 * t);
        buf[4 * t + 0] = x0 * rinv * g.x;
        buf[4 * t + 1] = x1 * rinv * g.y;
        buf[4 * t + 2] = x2 * rinv * g.z;
        buf[4 * t + 3] = x3 * rinv * g.w;
        __syncthreads();

        const float qsc = sel ? 1.0f : (0.125f * LOG2E);  // log2-domain scores

        #pragma unroll
        for (int pp = 0; pp < 2; ++pp) {
            const int p = t + pp * 256;
            const int h = p >> 5;
            const int r = p & 31;
            const int j = r & 15;
            const float pos = (r < 16) ? rowp : colp;
            const int d1 = (r < 16) ? j : (32 + j);   // within-head dim
            const int d2 = d1 + 16;
            const float freq = exp2f((float)j * -0.83048202372f);
            const float ang  = pos * freq;
            float sn, cs;
            __sincosf(ang, &sn, &cs);
            const float a1 = buf[h * HD + d1], a2 = buf[h * HD + d2];
            const float o1 = (a1 * cs - a2 * sn) * qsc;
            const float o2 = (a2 * cs + a1 * sn) * qsc;
            if (sel == 0) {
                row[h * HD + d1] = (half_t)o1;
                row[h * HD + d2] = (half_t)o2;
            } else {
                half_t* kdst = Kf + ((size_t)(b * HH + h) * 72 + fr) * 2048 + jt * 1024;
                kdst[(size_t)(d1 >> 5) * 512 + (km + 16 * ((d1 & 31) >> 3)) * 8 + (d1 & 7)]
                    = (half_t)o1;
                kdst[(size_t)(d2 >> 5) * 512 + (km + 16 * ((d2 & 31) >> 3)) * 8 + (d2 & 7)]
                    = (half_t)o2;
            }
        }
        __syncthreads();   // buf/red reused by next sel
    }
}

// ---------------------------------------------------------------------------
// Flash attention v6: register-direct K/V, ZERO barriers in the main loop.
// Wave w owns (j-tile jt=w&1, q-half qh=w>>1); K/V fragments load straight
// from the pre-swizzled global streams (4 x 16B coalesced per frame, L2-hot
// via the XCD swizzle), software-pipelined one frame ahead in registers.
// Slim per-wave tiling keeps ~100 VGPRs -> 4 waves/SIMD. LDS only for the
// one-time epilogue merge (stride-33 padding: conflict-free).
// ---------------------------------------------------------------------------
__global__ __launch_bounds__(256, 4)
void flash_attn_mfma6(const half_t* __restrict__ qkvh, const half_t* __restrict__ Kf,
                      const half_t* __restrict__ Vf, half_t* __restrict__ attn_h)
{
    const int flat = blockIdx.x;         // 0..1151, XCD-swizzled
    const int xcd  = flat & 7;
    const int jj   = flat >> 3;          // 0..143
    const int bh   = xcd * 4 + (jj / 36);
    const int qtb  = jj % 36;
    const int b    = bh >> 4, h = bh & 15;
    const int t    = threadIdx.x;
    const int w    = t >> 6;
    const int jt   = w & 1;              // wave's j-tile within each frame
    const int qh   = w >> 1;             // wave's q-half (32 q rows)
    const int lane = t & 63;
    const int l15  = lane & 15, quad = lane >> 4;

    const size_t tb = (size_t)b * SS;
    const int q0 = qtb * 64;

    __shared__ float mlb[4][32][2];      // per-wave (m, l) for its 32 q's
    __shared__ float Ob[2][64][33];      // [qh][d][q], padded stride 33

    // Q B-frags (loop invariant): B[k=quad*8+i][n=l15], 2 q-tiles of this q-half
    half8 qf[2][2];
    #pragma unroll
    for (int qt = 0; qt < 2; ++qt)
        #pragma unroll
        for (int dt2 = 0; dt2 < 2; ++dt2)
            qf[qt][dt2] = *(const half8*)(qkvh + (tb + q0 + qh * 32 + qt * 16 + l15) * 3072
                                          + h * HD + dt2 * 32 + quad * 8);

    f32x4 acc[4][2];                     // [dt][qt] : O^T[dt*16+quad*4+reg][q]
    float m_i[2], l_i[2];
    #pragma unroll
    for (int qt = 0; qt < 2; ++qt) {
        m_i[qt] = -INFINITY; l_i[qt] = 0.f;
        #pragma unroll
        for (int dt = 0; dt < 4; ++dt) acc[dt][qt] = (f32x4){0.f, 0.f, 0.f, 0.f};
    }

    // wave's per-frame load pointers (16B/lane, coalesced 1KB per half8 pair)
    const half_t* kpl = Kf + (size_t)bh * 72 * 2048 + jt * 1024 + lane * 8;
    const half_t* vpl = Vf + (size_t)bh * 72 * 2048 + jt * 1024 + lane * 8;

    // one frame of compute: QK^T -> online softmax -> PV
    auto step = [&](half8 kf0, half8 kf1, half8 v01, half8 v23) {
        half4 vf[4] = {lo4(v01), hi4(v01), lo4(v23), hi4(v23)};
        f32x4 sc[2];
        #pragma unroll
        for (int qt = 0; qt < 2; ++qt) {
            sc[qt] = (f32x4){0.f, 0.f, 0.f, 0.f};
            sc[qt] = __builtin_amdgcn_mfma_f32_16x16x32_f16(kf0, qf[qt][0], sc[qt], 0, 0, 0);
            sc[qt] = __builtin_amdgcn_mfma_f32_16x16x32_f16(kf1, qf[qt][1], sc[qt], 0, 0, 0);
        }
        half4 pf[2];
        #pragma unroll
        for (int qt = 0; qt < 2; ++qt) {
            float mx = fmaxf(fmaxf(sc[qt][0], sc[qt][1]), fmaxf(sc[qt][2], sc[qt][3]));
            mx = fmaxf(mx, __shfl_xor(mx, 16));
            mx = fmaxf(mx, __shfl_xor(mx, 32));
            if (__any(mx > m_i[qt])) {
                const float mn = fmaxf(m_i[qt], mx);
                const float alpha = EXP2(m_i[qt] - mn);
                m_i[qt] = mn;
                l_i[qt] *= alpha;
                #pragma unroll
                for (int dt = 0; dt < 4; ++dt) acc[dt][qt] *= alpha;
            }
            const float m = m_i[qt];
            const float p0 = EXP2(sc[qt][0] - m);
            const float p1 = EXP2(sc[qt][1] - m);
            const float p2 = EXP2(sc[qt][2] - m);
            const float p3 = EXP2(sc[qt][3] - m);
            l_i[qt] += (p0 + p1) + (p2 + p3);
            pf[qt] = (half4){(half_t)p0, (half_t)p1, (half_t)p2, (half_t)p3};
        }
        #pragma unroll
        for (int dt = 0; dt < 4; ++dt)
            #pragma unroll
            for (int qt = 0; qt < 2; ++qt)
                acc[dt][qt] = __builtin_amdgcn_mfma_f32_16x16x16f16(
                    vf[dt], pf[qt], acc[dt][qt], 0, 0, 0);
    };

    // software pipeline: register double-buffer, distance-1 prefetch
    half8 kA0 = *(const half8*)(kpl);
    half8 kA1 = *(const half8*)(kpl + 512);
    half8 vA0 = *(const half8*)(vpl);
    half8 vA1 = *(const half8*)(vpl + 512);

    for (int fr2 = 0; fr2 < 36; ++fr2) {
        const int fr = fr2 * 2;
        // prefetch frame fr+1 (always exists: fr <= 70)
        const half_t* kB = kpl + (size_t)(fr + 1) * 2048;
        const half_t* vB = vpl + (size_t)(fr + 1) * 2048;
        half8 kB0 = *(const half8*)(kB);
        half8 kB1 = *(const half8*)(kB + 512);
        half8 vB0 = *(const half8*)(vB);
        half8 vB1 = *(const half8*)(vB + 512);

        step(kA0, kA1, vA0, vA1);

        if (fr + 2 < 72) {               // prefetch frame fr+2
            const half_t* kA = kpl + (size_t)(fr + 2) * 2048;
            const half_t* vA = vpl + (size_t)(fr + 2) * 2048;
            kA0 = *(const half8*)(kA);
            kA1 = *(const half8*)(kA + 512);
            vA0 = *(const half8*)(vA);
            vA1 = *(const half8*)(vA + 512);
        }

        step(kB0, kB1, vB0, vB1);
    }

    // ---- 2-way merge: waves (jt=0, jt=1) of the same q-half ----
    #pragma unroll
    for (int qt = 0; qt < 2; ++qt) {      // cross-quad reduce lane-local l
        float lq = l_i[qt];
        lq += __shfl_xor(lq, 16);
        lq += __shfl_xor(lq, 32);
        if (quad == 0) {
            mlb[w][qt * 16 + l15][0] = m_i[qt];
            mlb[w][qt * 16 + l15][1] = lq;
        }
    }
    __syncthreads();

    float fac[2];
    #pragma unroll
    for (int qt = 0; qt < 2; ++qt) {
        const int q = qt * 16 + l15;
        const float m0 = mlb[qh * 2 + 0][q][0], m1 = mlb[qh * 2 + 1][q][0];
        const float M  = fmaxf(m0, m1);
        const float L  = mlb[qh * 2 + 0][q][1] * EXP2(m0 - M)
                       + mlb[qh * 2 + 1][q][1] * EXP2(m1 - M);
        fac[qt] = EXP2(m_i[qt] - M) / L;
    }

    #pragma unroll
    for (int ph = 0; ph < 2; ++ph) {
        if (jt == ph) {
            #pragma unroll
            for (int dt = 0; dt < 4; ++dt)
                #pragma unroll
                for (int qt = 0; qt < 2; ++qt)
                    #pragma unroll
                    for (int rg = 0; rg < 4; ++rg) {
                        const int d = dt * 16 + quad * 4 + rg;
                        const int q = qt * 16 + l15;
                        const float v = acc[dt][qt][rg] * fac[qt];
                        if (ph == 0) Ob[qh][d][q] = v;
                        else         Ob[qh][d][q] += v;
                    }
        }
        __syncthreads();
    }

    // ---- store O as f16, tile-blocked [mb][kb][128][32] for the proj GEMM ----
    {
        const int q   = t >> 2;              // token within q-tile (0..63)
        const int ds  = (t & 3) * 16;
        const int qh2 = q >> 5, qq = q & 31;
        const size_t mrow = tb + q0 + q;
        const int mb2 = (int)(mrow >> 7);
        const int mm  = (int)(mrow & 127);
        #pragma unroll
        for (int g = 0; g < 4; ++g) {
            const int dd = ds + 4 * g;
            const int kb2 = (h * HD + dd) >> 5;
            const int kk  = dd & 31;
            half4 o;
            o[0] = (half_t)Ob[qh2][dd + 0][qq];
            o[1] = (half_t)Ob[qh2][dd + 1][qq];
            o[2] = (half_t)Ob[qh2][dd + 2][qq];
            o[3] = (half_t)Ob[qh2][dd + 3][qq];
            *(half4*)(attn_h + ((size_t)mb2 * 32 + kb2) * 4096 + mm * 32 + kk) = o;
        }
    }
}

// ---------------------------------------------------------------------------
// Launch
// ---------------------------------------------------------------------------
extern "C" void kernel_launch(void* const* d_in, const int* in_sizes, int n_in,
                              void* d_out, int out_size, void* d_ws, size_t ws_size,
                              hipStream_t stream)
{
    const float* input   = (const float*)d_in[0];
    const float* qkv_w   = (const float*)d_in[1];
    const float* qkv_b   = (const float*)d_in[2];
    const float* q_scale = (const float*)d_in[3];
    const float* k_scale = (const float*)d_in[4];
    const float* proj_w  = (const float*)d_in[5];
    const float* proj_b  = (const float*)d_in[6];
    const int*   width   = (const int*)d_in[8];
    float* out = (float*)d_out;

    // ws layout (all f16): qkv_h 28.3MB | attn_h 9.4 | Vf 9.4 | Ah 9.4 (reused
    // as Kf after GEMM1) | Bh1 6.3 | Bh2 2.1  => 65.0 MB total
    half_t* qkvh   = (half_t*)d_ws;
    half_t* attn_h = qkvh   + (size_t)4608 * 3072;
    half_t* Vf     = attn_h + (size_t)4608 * 1024;
    half_t* Ah     = Vf     + (size_t)32 * 72 * 2048;
    half_t* Bh1    = Ah     + (size_t)4608 * 1024;
    half_t* Bh2    = Bh1    + (size_t)3072 * 1024;
    half_t* Kf     = Ah;    // Ah is dead after GEMM1; Kf is written by normrope

    const int M = BB * SS;   // 4608

    // 0) fp32 -> f16 tile-blocked converters (proj_w 64-row-blocked)
    convert_tile_f16<128><<<dim3(M / 128, DINC / 32),        256, 0, stream>>>(input,  Ah,  DINC);
    convert_tile_f16<128><<<dim3(3 * DIMC / 128, DINC / 32), 256, 0, stream>>>(qkv_w, Bh1, DINC);
    convert_tile_f16<64><<<dim3(DINC / 64, DIMC / 32),       256, 0, stream>>>(proj_w, Bh2, DIMC);

    // 1) qkv_h = f16( input @ qkv_w^T + qkv_b )
    gemm_mfma<128, true><<<dim3(3 * DIMC / 128, M / 128), 256, 0, stream>>>(
        Ah, Bh1, qkv_b, qkvh, M, 3 * DIMC, DINC);

    // 2) RMSNorm + RoPE: Q in place (log2-scaled), K -> Kf, V -> Vf
    normrope_v6<<<M, 256, 0, stream>>>(qkvh, q_scale, k_scale, width, Kf, Vf);

    // 3) MFMA flash attention -> attn_h (f16, tile-blocked), XCD-swizzled
    flash_attn_mfma6<<<dim3(SS / 64 * BB * HH), 256, 0, stream>>>(qkvh, Kf, Vf, attn_h);

    // 4) out = attn @ proj_w^T + proj_b  (fp32 out, BN=64 for occupancy)
    gemm_mfma<64, false><<<dim3(DINC / 64, M / 128), 256, 0, stream>>>(
        attn_h, Bh2, proj_b, out, M, DINC, DIMC);
}